// Round 8
// baseline (355.293 us; speedup 1.0000x reference)
//
#include <hip/hip_runtime.h>

// LovaszSoftmaxLoss B=8, C=21, H=W=512 — sort-free counting-sort formulation.
// loss = sum_i e_i*(g_i - g_{i-1}) over descending-sorted errors; equal-key
// runs contribute e*(g(b)-g(a-1)) independent of tie order, so a histogram
// over quantized keys suffices. Key = 12 octaves x 6 mantissa bits = 768 bins.
//
// R11 post-mortem: k_fused fell under the 102us top-5 cutoff but total only
// moved 287->284 (noise +-10). Fit over R8/R9/R10 (k_fused visible) gives
// harness-fixed ~165-175us => R11 k_fused still ~100us. Invariant suspect:
// phase-2 re-reads x as 21 streams at EXACTLY 1MB stride -> 1MB-congruent
// addresses alias one L2 set (4MB 16-way, 1MB period); 21 > 16 ways => the
// block's own re-reads thrash L2 and eat LLC latency (FETCH stays ~176MB, so
// it's latency not traffic — matches 21% HBM / 23% VALU / nothing saturated).
// R12: touch x ONCE. Phase 1: coalesced scalar reads, Z += expf, stash fp16
// in LDS (43KB; err <=0.4% on e, bin width 1.1%). Phase 2: 3 groups x 7
// classes, 7x768-bin LDS hists (21KB), nonzero-only flush to global u64 hist
// (R8-verified scan). LDS 64KB -> 2 blocks/CU = 32 waves (full); VGPR<=64.
// Predict: k_fused ~100 -> 40-60us, occ >=80%, total -> 225-255us.

#define NB     8
#define NC     21
#define NPIX   262144
#define NROWS  (NB * NC)       // 168
#define NBINS  768             // key = (fexp+12)<<6 | mant6 ; fexp in [-12,0]
#define CHUNK  1024            // pixels per block
#define CPB    (NPIX / CHUNK)  // 256 chunks per batch
#define G      7               // classes per hist group (3 groups)

// ---------------- Fused kernel: stage-once -> Z -> class-group hists -> global merge ----
// 2048 blocks x 1024 threads, 1 px/thread. LDS bin u32 = count<<18 | labelsum
// (count<=1024, labelsum<=20480 < 2^18). Global u64 = count<<32 | labelsum.
__global__ __launch_bounds__(1024, 8) void k_fused(
    const float* __restrict__ x,
    const int* __restrict__ tgt,
    unsigned long long* __restrict__ ghist) {
  __shared__ _Float16 stage[NC][CHUNK];    // 43 KB
  __shared__ unsigned hist[G * NBINS];     // 21 KB
  int tid   = threadIdx.x;
  int b     = blockIdx.x >> 8;             // / CPB
  int chunk = blockIdx.x & (CPB - 1);
  const float* xb = x + (size_t)b * NC * NPIX + (size_t)chunk * CHUNK;

  for (int i = tid; i < G * NBINS; i += 1024) hist[i] = 0;

  // ---- phase 1: read x once (coalesced), Z in one register, stash fp16 ----
  // no max-sub: N(0,1) logits bounded, exp safe in f32.
  float Z = 0.f;
  #pragma unroll
  for (int c = 0; c < NC; ++c) {
    float t = xb[(size_t)c * NPIX + tid];
    Z += __expf(t);
    stage[c][tid] = (_Float16)t;
  }
  float L = __logf(Z);
  unsigned lab = (unsigned)tgt[(size_t)b * NPIX + (size_t)chunk * CHUNK + tid];
  __syncthreads();                         // hist zeroed + stage filled

  // ---- phase 2: 3 groups of 7 classes; bin from LDS; flush nonzero bins ----
  unsigned long long* gh = ghist + (size_t)b * NC * NBINS;
  for (int grp = 0; grp < 3; ++grp) {
    #pragma unroll
    for (int j = 0; j < G; ++j) {
      int c = grp * G + j;
      float xv = (float)stage[c][tid];
      float p  = __expf(xv - L);
      float e  = fabsf(((c == (int)lab) ? 1.0f : 0.0f) - p);   // e in [0,1]
      unsigned fb = __float_as_uint(e);
      int      fx = (int)(fb >> 23) - 127;
      unsigned k;
      if (fx < -12) k = 0u;
      else {
        k = (((unsigned)(fx + 12)) << 6) | ((fb >> 17) & 63u);
        if (k > NBINS - 1) k = NBINS - 1;                      // e==1.0 / safety
      }
      atomicAdd(hist + j * NBINS + k, (1u << 18) | lab);
    }
    __syncthreads();
    for (int i = tid; i < G * NBINS; i += 1024) {
      unsigned v = hist[i];
      if (v) {
        int j = i / NBINS, bin = i - j * NBINS;
        atomicAdd(gh + (size_t)(grp * G + j) * NBINS + bin,
                  ((unsigned long long)(v >> 18) << 32) |
                  (unsigned long long)(v & 0x3FFFFu));
        hist[i] = 0;
      }
    }
    __syncthreads();
  }
}

// ---------------- u64 shuffle helpers ----------------
__device__ inline unsigned long long shfl_up_u64(unsigned long long v, int off) {
  unsigned lo = (unsigned)v, hi = (unsigned)(v >> 32);
  lo = (unsigned)__shfl_up((int)lo, off, 64);
  hi = (unsigned)__shfl_up((int)hi, off, 64);
  return ((unsigned long long)hi << 32) | lo;
}
__device__ inline unsigned long long shfl_down_u64(unsigned long long v, int off) {
  unsigned lo = (unsigned)v, hi = (unsigned)(v >> 32);
  lo = (unsigned)__shfl_down((int)lo, off, 64);
  hi = (unsigned)__shfl_down((int)hi, off, 64);
  return ((unsigned long long)hi << 32) | lo;
}

// ---------------- Scan kernel: descending scan over 768 bins (R8-verified) ----------------
// 168 blocks x 768 threads (12 waves); one thread per bin; single u64 load.
__global__ __launch_bounds__(768) void k_scan(
    const unsigned long long* __restrict__ ghist,
    float* __restrict__ out) {
  int row  = blockIdx.x;                     // 0..167  (= b*NC + c)
  int tid  = threadIdx.x;                    // == bin slot
  int lane = tid & 63;
  int wave = tid >> 6;                       // 12 waves

  __shared__ unsigned long long hist0[NBINS];   // 6 KB
  __shared__ unsigned long long wtot[12];
  __shared__ double wred[12];
  __shared__ double sT;

  hist0[tid] = ghist[(size_t)row * NBINS + tid];
  __syncthreads();

  // total labelsum T (exact; fields can't overflow: cnt<=262144, ls<=5.3M)
  unsigned long long tot = hist0[tid];
  #pragma unroll
  for (int off = 32; off > 0; off >>= 1) tot += shfl_down_u64(tot, off);
  if (lane == 0) wtot[wave] = tot;
  __syncthreads();
  if (tid == 0) {
    unsigned long long g = 0;
    #pragma unroll
    for (int w = 0; w < 12; ++w) g += wtot[w];
    sT = (double)(unsigned)(g & 0xffffffffULL);
  }
  __syncthreads();
  double T = sT;
  __syncthreads();

  // single-chunk descending scan over 768 bins
  int bin = (NBINS - 1) - tid;
  unsigned long long v = hist0[bin];

  unsigned long long s = v;                  // intra-wave inclusive scan
  #pragma unroll
  for (int off = 1; off < 64; off <<= 1) {
    unsigned long long u = shfl_up_u64(s, off);
    if (lane >= off) s += u;
  }
  if (lane == 63) wtot[wave] = s;
  __syncthreads();

  unsigned long long woff = 0;
  for (int w = 0; w < wave; ++w) woff += wtot[w];
  unsigned long long excl = s - v + woff;    // strictly-greater prefix

  double acc = 0.0;
  unsigned n = (unsigned)(v >> 32);
  if (n) {
    unsigned sl = (unsigned)(v & 0xffffffffu);
    unsigned cb = (unsigned)(excl >> 32);
    unsigned sb = (unsigned)(excl & 0xffffffffu);
    double Sb = (double)sb + (double)sl;
    double gb = 1.0 - (T - Sb) / (T + (double)(cb + n) - Sb);
    double ga = (cb == 0) ? 0.0
                          : 1.0 - (T - (double)sb) / (T + (double)cb - (double)sb);
    unsigned key = (unsigned)bin;
    unsigned ex  = key >> 6, mant = key & 63u;
    float e = ldexpf(1.0f + ((float)mant + 0.5f) * 0.015625f, (int)ex - 12);
    acc = (double)e * (gb - ga);
  }

  // block reduce acc (12 waves)
  #pragma unroll
  for (int off = 32; off > 0; off >>= 1) acc += __shfl_down(acc, off, 64);
  if (lane == 0) wred[wave] = acc;
  __syncthreads();
  if (tid == 0) {
    double ssum = 0.0;
    #pragma unroll
    for (int w = 0; w < 12; ++w) ssum += wred[w];
    atomicAdd(out, (float)(ssum * (1.0 / (double)NROWS)));
  }
}

extern "C" void kernel_launch(void* const* d_in, const int* in_sizes, int n_in,
                              void* d_out, int out_size, void* d_ws, size_t ws_size,
                              hipStream_t stream) {
  const float* x  = (const float*)d_in[0];   // (B, C, H, W) float32
  const int* tgt  = (const int*)d_in[1];     // (B, H, W) int32
  float* out      = (float*)d_out;
  unsigned long long* ghist = (unsigned long long*)d_ws;  // 168*768*8 = 1.03 MB

  hipMemsetAsync(d_out, 0, sizeof(float), stream);
  hipMemsetAsync(ghist, 0, (size_t)NROWS * NBINS * sizeof(unsigned long long), stream);
  k_fused<<<NB * CPB, 1024, 0, stream>>>(x, tgt, ghist);
  k_scan<<<NROWS, NBINS, 0, stream>>>(ghist, out);
}

// Round 9
// 282.504 us; speedup vs baseline: 1.2577x; 1.2577x over previous
//
#include <hip/hip_runtime.h>

// LovaszSoftmaxLoss B=8, C=21, H=W=512 — sort-free counting-sort formulation.
// loss = sum_i e_i*(g_i - g_{i-1}) over descending-sorted errors; equal-key
// runs contribute e*(g(b)-g(a-1)) independent of tie order, so a histogram
// over quantized keys suffices. Key = 12 octaves x 6 mantissa bits = 768 bins.
//
// R12 post-mortem: WRITE=163MB == ~20M u64 memory-side atomic RMWs (the
// nonzero-bin flush) at ~6-8ns each ~= 130us -> global atomics PRICED, never
// again in millions. Occupancy 41->74% left VALUBusy pinned at 24% -> never
// VALU-bound; the ~104us floor of atomic-free variants is latency/serial
// structure (per-class barriers + shared-hist contention), not traffic.
// R13: barrier-free contention-free phase 2.
//  - Phase 1: thread owns 4 px; 21 indep float4 loads; Z += exp2(x*LOG2E);
//    L2=log2(Z) as fp16 + labels u8 -> LDS (12 KB).
//  - Phase 2: 42 items (class, half) dealt to 16 waves; each class hist
//    owned by <=2 waves; ZERO barriers; rolling prefetch; branchless bin
//    key = clamp((bits(e)>>17)-7360, 0, 767); ds_add only (LDS atomics).
//  - LDS 75 KB -> 2 blocks/CU = 32 waves (100%); launch_bounds(1024,8).
//  - Flush = plain partial write (33 MB); R11-verified 64-way merge scan.
// Predict: k_fused 104 -> 45-60us, WRITE ~35MB, occ ~100%; total ~215-245.

#define NB     8
#define NC     21
#define NPIX   262144
#define NROWS  (NB * NC)       // 168
#define NBINS  768             // key = (fexp+12)<<6 | mant6 ; fexp in [-12,0]
#define CHUNKS 64              // blocks per batch
#define CHUNK  (NPIX / CHUNKS) // 4096 pixels per block
#define LOG2E  1.4426950408889634f

// ---------------- Fused kernel ----------------
// 512 blocks x 1024 threads. LDS bin u32 = count<<18 | labelsum
// (count<=4096 -> <<18 caps 2^30, labelsum<=81920 < 2^18).
__global__ __launch_bounds__(1024, 8) void k_fused(
    const float* __restrict__ x,
    const int* __restrict__ tgt,
    unsigned* __restrict__ partial) {
  __shared__ unsigned      hist[NC * NBINS];  // 63 KB
  __shared__ _Float16      Ls[CHUNK];         // 8 KB  (L2 = log2 Z per px)
  __shared__ unsigned char labs[CHUNK];       // 4 KB

  int tid   = threadIdx.x;
  int b     = blockIdx.x >> 6;
  int chunk = blockIdx.x & 63;
  const float* xb = x + (size_t)b * NC * NPIX + (size_t)chunk * CHUNK;

  for (int i = tid; i < NC * NBINS; i += 1024) hist[i] = 0;

  // ---- phase 1: Z over 21 classes for this thread's 4 px; stash L2 + labels ----
  // no max-sub: N(0,1) logits bounded, exp2 safe in f32.
  int n4 = tid * 4;
  float Z0 = 0.f, Z1 = 0.f, Z2 = 0.f, Z3 = 0.f;
  #pragma unroll
  for (int c = 0; c < NC; ++c) {
    float4 t = *(const float4*)(xb + (size_t)c * NPIX + n4);
    Z0 += exp2f(t.x * LOG2E);
    Z1 += exp2f(t.y * LOG2E);
    Z2 += exp2f(t.z * LOG2E);
    Z3 += exp2f(t.w * LOG2E);
  }
  Ls[n4 + 0] = (_Float16)__log2f(Z0);
  Ls[n4 + 1] = (_Float16)__log2f(Z1);
  Ls[n4 + 2] = (_Float16)__log2f(Z2);
  Ls[n4 + 3] = (_Float16)__log2f(Z3);
  {
    int4 tv = *(const int4*)(tgt + (size_t)b * NPIX + (size_t)chunk * CHUNK + n4);
    *(unsigned*)(labs + n4) = (unsigned)tv.x | ((unsigned)tv.y << 8) |
                              ((unsigned)tv.z << 16) | ((unsigned)tv.w << 24);
  }
  __syncthreads();   // hist zeroed + Ls/labs staged

  // ---- phase 2: 42 items = (class, half); wave-owned hists; NO barriers ----
  int wave = tid >> 6, lane = tid & 63;
  struct H4 { _Float16 v[4]; };
  for (int ii = wave; ii < 2 * NC; ii += 16) {
    int c = ii >> 1, h = ii & 1;
    const float* xc = xb + (size_t)c * NPIX + h * 2048;
    unsigned* hc = hist + c * NBINS;

    float4 nxt = *(const float4*)(xc + lane * 4);
    #pragma unroll
    for (int it = 0; it < 8; ++it) {
      float4 cur = nxt;
      if (it < 7) nxt = *(const float4*)(xc + (it + 1) * 256 + lane * 4);
      int px = h * 2048 + it * 256 + lane * 4;
      H4 l4 = *(const H4*)(Ls + px);
      unsigned lb = *(const unsigned*)(labs + px);
      float xs[4] = {cur.x, cur.y, cur.z, cur.w};
      #pragma unroll
      for (int j = 0; j < 4; ++j) {
        float L2q = (float)l4.v[j];
        float p   = exp2f(fmaf(xs[j], LOG2E, -L2q));   // softmax prob
        unsigned lab = (lb >> (8 * j)) & 255u;
        float sel = ((int)lab == c) ? 1.0f : 0.0f;
        float e   = fabsf(sel - p);                    // e in [0,1]
        int k = (int)(__float_as_uint(e) >> 17) - 7360; // ((fexp+12)<<6)|mant6
        k = min(max(k, 0), NBINS - 1);                 // e<2^-12 -> 0; e>=1 -> top
        atomicAdd(hc + k, (1u << 18) | lab);
      }
    }
  }
  __syncthreads();

  unsigned* op = partial + (size_t)blockIdx.x * NC * NBINS;
  for (int i = tid; i < NC * NBINS; i += 1024) op[i] = hist[i];
}

// ---------------- u64 shuffle helpers ----------------
__device__ inline unsigned long long shfl_up_u64(unsigned long long v, int off) {
  unsigned lo = (unsigned)v, hi = (unsigned)(v >> 32);
  lo = (unsigned)__shfl_up((int)lo, off, 64);
  hi = (unsigned)__shfl_up((int)hi, off, 64);
  return ((unsigned long long)hi << 32) | lo;
}
__device__ inline unsigned long long shfl_down_u64(unsigned long long v, int off) {
  unsigned lo = (unsigned)v, hi = (unsigned)(v >> 32);
  lo = (unsigned)__shfl_down((int)lo, off, 64);
  hi = (unsigned)__shfl_down((int)hi, off, 64);
  return ((unsigned long long)hi << 32) | lo;
}

// ---------------- Scan kernel: merge 64 partials/row + descending scan ----------------
// 168 blocks x 768 threads (12 waves); one thread per bin. (Verified R11.)
__global__ __launch_bounds__(768) void k_scan(
    const unsigned* __restrict__ partial,
    float* __restrict__ out) {
  int row  = blockIdx.x;                     // 0..167
  int b    = row / NC;
  int c    = row - b * NC;
  int tid  = threadIdx.x;                    // == bin slot
  int lane = tid & 63;
  int wave = tid >> 6;                       // 12 waves

  __shared__ unsigned long long hist0[NBINS];   // 6 KB
  __shared__ unsigned long long wtot[12];
  __shared__ double wred[12];
  __shared__ double sT;

  // merge 64 block-partials for (b, c): coalesced 768-wide loads
  {
    const unsigned* pp = partial + ((size_t)(b * CHUNKS) * NC + c) * NBINS + tid;
    unsigned long long cnt = 0, ls = 0;
    #pragma unroll 8
    for (int j = 0; j < CHUNKS; ++j) {
      unsigned v = pp[(size_t)j * NC * NBINS];
      cnt += (v >> 18);
      ls  += (v & 0x3FFFFu);
    }
    hist0[tid] = (cnt << 32) | ls;
  }
  __syncthreads();

  // total labelsum T (exact; fields can't overflow: cnt<=262144, ls<=5.3M)
  unsigned long long tot = hist0[tid];
  #pragma unroll
  for (int off = 32; off > 0; off >>= 1) tot += shfl_down_u64(tot, off);
  if (lane == 0) wtot[wave] = tot;
  __syncthreads();
  if (tid == 0) {
    unsigned long long g = 0;
    #pragma unroll
    for (int w = 0; w < 12; ++w) g += wtot[w];
    sT = (double)(unsigned)(g & 0xffffffffULL);
  }
  __syncthreads();
  double T = sT;
  __syncthreads();

  // single-chunk descending scan over 768 bins
  int bin = (NBINS - 1) - tid;
  unsigned long long v = hist0[bin];

  unsigned long long s = v;                  // intra-wave inclusive scan
  #pragma unroll
  for (int off = 1; off < 64; off <<= 1) {
    unsigned long long u = shfl_up_u64(s, off);
    if (lane >= off) s += u;
  }
  if (lane == 63) wtot[wave] = s;
  __syncthreads();

  unsigned long long woff = 0;
  for (int w = 0; w < wave; ++w) woff += wtot[w];
  unsigned long long excl = s - v + woff;    // strictly-greater prefix

  double acc = 0.0;
  unsigned n = (unsigned)(v >> 32);
  if (n) {
    unsigned sl = (unsigned)(v & 0xffffffffu);
    unsigned cb = (unsigned)(excl >> 32);
    unsigned sb = (unsigned)(excl & 0xffffffffu);
    double Sb = (double)sb + (double)sl;
    double gb = 1.0 - (T - Sb) / (T + (double)(cb + n) - Sb);
    double ga = (cb == 0) ? 0.0
                          : 1.0 - (T - (double)sb) / (T + (double)cb - (double)sb);
    unsigned key = (unsigned)bin;
    unsigned ex  = key >> 6, mant = key & 63u;
    float e = ldexpf(1.0f + ((float)mant + 0.5f) * 0.015625f, (int)ex - 12);
    acc = (double)e * (gb - ga);
  }

  // block reduce acc (12 waves)
  #pragma unroll
  for (int off = 32; off > 0; off >>= 1) acc += __shfl_down(acc, off, 64);
  if (lane == 0) wred[wave] = acc;
  __syncthreads();
  if (tid == 0) {
    double ssum = 0.0;
    #pragma unroll
    for (int w = 0; w < 12; ++w) ssum += wred[w];
    atomicAdd(out, (float)(ssum * (1.0 / (double)NROWS)));
  }
}

extern "C" void kernel_launch(void* const* d_in, const int* in_sizes, int n_in,
                              void* d_out, int out_size, void* d_ws, size_t ws_size,
                              hipStream_t stream) {
  const float* x  = (const float*)d_in[0];   // (B, C, H, W) float32
  const int* tgt  = (const int*)d_in[1];     // (B, H, W) int32
  float* out      = (float*)d_out;
  unsigned* partial = (unsigned*)d_ws;       // 512*21*768*4 = 33 MB

  hipMemsetAsync(d_out, 0, sizeof(float), stream);
  k_fused<<<NB * CHUNKS, 1024, 0, stream>>>(x, tgt, partial);
  k_scan<<<NROWS, NBINS, 0, stream>>>(partial, out);
}